// Round 9
// baseline (227.066 us; speedup 1.0000x reference)
//
#include <hip/hip_runtime.h>
#include <cstdint>

#define BB 8
#define SQ 1024
#define HH 1024
#define NH 16
#define HD 64

typedef __attribute__((ext_vector_type(4))) float f32x4;
typedef __attribute__((ext_vector_type(16))) float f32x16;
typedef __attribute__((ext_vector_type(8))) __bf16 bf16x8;
typedef __attribute__((ext_vector_type(8))) unsigned short u16x8;
typedef __attribute__((ext_vector_type(4))) unsigned short u16x4;
typedef __attribute__((ext_vector_type(4))) unsigned int u32x4;

__device__ __forceinline__ unsigned short f2bf(float f){
  uint32_t u = __builtin_bit_cast(uint32_t, f);
  u += 0x7FFFu + ((u >> 16) & 1u);
  return (unsigned short)(u >> 16);
}

__device__ __forceinline__ void gload_lds16(const void* g, void* l){
  __builtin_amdgcn_global_load_lds((__attribute__((address_space(1))) void*)g,
                                   (__attribute__((address_space(3))) void*)l,
                                   16, 0, 0);
}

// ---------------- fused prep: convert X fp32->bf16  +  W transpose/convert ----------------
__global__ __launch_bounds__(256) void k_prep(const float* __restrict__ x,
                                              unsigned short* __restrict__ xb,
                                              const float* __restrict__ Wq,
                                              const float* __restrict__ Wk,
                                              const float* __restrict__ Wv,
                                              unsigned short* __restrict__ wt){
  __shared__ float t[32][33];
  int bid = blockIdx.x, tid = threadIdx.x;
  if(bid < 4096){
    int i = bid * 256 + tid;
    const f32x4* xv = (const f32x4*)x;
    f32x4 a = xv[2*i], b = xv[2*i+1];
    u16x8 o;
    o[0]=f2bf(a[0]); o[1]=f2bf(a[1]); o[2]=f2bf(a[2]); o[3]=f2bf(a[3]);
    o[4]=f2bf(b[0]); o[5]=f2bf(b[1]); o[6]=f2bf(b[2]); o[7]=f2bf(b[3]);
    ((u16x8*)xb)[i] = o;
  } else {
    int idx = bid - 4096;
    int p = idx >> 10, rem = idx & 1023;
    const float* W = (p==0)?Wq:((p==1)?Wk:Wv);
    int n0 = (rem & 31)*32, k0 = (rem >> 5)*32;
    int tx = tid & 31, ty = tid >> 5;
    #pragma unroll
    for(int j=0;j<32;j+=8) t[ty+j][tx] = W[(size_t)(k0+ty+j)*HH + n0+tx];
    __syncthreads();
    unsigned short* o = wt + (size_t)p*HH*HH;
    #pragma unroll
    for(int j=0;j<32;j+=8) o[(size_t)(n0+ty+j)*HH + k0+tx] = f2bf(t[tx][ty+j]);
  }
}

// ---------------- fused QKV GEMM: 4-phase counted-vmcnt schedule, 2-buffer ----------------
// 256x128 tile, BK=64, 512 thr = 8 waves (2M x 4N), per-wave 128x32 output.
// Units/tile: a0(rows 0-127, 2 loads) a1(rows 128-255, 2) b0/b1(n-halves, 1 each).
// Quadrants (mh,ks): ph0=(0,0) ph1=(1,0) ph2=(0,1) ph3=(1,1). Region last-reads:
// A-half0@ph2, A-half1@ph3, B@ph3 -> safe stagger: ph0:a1(t+1) ph1:b0(t+1)
// ph2:b1(t+1) ph3:a0(t+2)->cur-buf. Tile-boundary wait = vmcnt(2) (a0(t+2) in
// flight), never 0 until the tail. Phase = reads|stage|bar|setprio-MFMA|bar.
#define QBM 256
#define QBN 128
#define QBK 64
__global__ __launch_bounds__(512, 2) void k_qkv(const unsigned short* __restrict__ Xb,
                                                const unsigned short* __restrict__ Wt,
                                                const float* __restrict__ bq,
                                                const float* __restrict__ bk,
                                                const float* __restrict__ bv,
                                                unsigned short* __restrict__ q_ws,
                                                unsigned short* __restrict__ k_ws,
                                                unsigned short* __restrict__ vt_ws){
  __shared__ __align__(16) unsigned short As[2][QBM*QBK];   // 2 x 32 KB
  __shared__ __align__(16) unsigned short Bs[2][QBN*QBK];   // 2 x 16 KB
  int tid = threadIdx.x;
  int lane = tid & 63, wid = tid >> 6;
  int wr = wid >> 2, wc = wid & 3;          // 2M x 4N wave grid
  int bid = blockIdx.x;
  int sw = (bid & 7)*96 + (bid >> 3);       // XCD-bijective (768 = 8*96)
  int nt = sw % 24, mt = sw / 24;
  int m0 = mt*QBM, n0 = nt*QBN;
  int lr = lane & 15, g = lane >> 4;
  int srow = tid >> 3;
  int sch  = (tid & 7) ^ (srow & 7);

  const f32x4 zf = {0.f,0.f,0.f,0.f};
  f32x4 acc[8][2];
  #pragma unroll
  for(int a=0;a<8;a++){ acc[a][0] = zf; acc[a][1] = zf; }

  // unit staging: A unit u (0=rows 0-127, 1=rows 128-255), sub-load it (64 rows)
  #define ST_A(buf, kb, u, it) gload_lds16( \
      Xb + (size_t)(m0 + (u)*128 + (it)*64 + srow)*1024 + (kb) + sch*8, \
      &As[buf][(((u)*2+(it))*512 + tid)*8])
  #define ST_B(buf, kb, h) gload_lds16( \
      Wt + (size_t)(n0 + (h)*64 + srow)*1024 + (kb) + sch*8, \
      &Bs[buf][((h)*512 + tid)*8])

  // prologue: tile 0 complete (6 loads) + a0 of tile 1 (2 loads)
  ST_A(0,0,0,0); ST_A(0,0,0,1); ST_A(0,0,1,0); ST_A(0,0,1,1);
  ST_B(0,0,0);   ST_B(0,0,1);
  ST_A(1,QBK,0,0); ST_A(1,QBK,0,1);
  asm volatile("s_waitcnt vmcnt(2)" ::: "memory");   // tile 0 landed
  __builtin_amdgcn_s_barrier();

  for(int kt=0; kt<16; kt++){
    int cur = kt & 1, nxt = cur ^ 1;
    const unsigned short* Ab = As[cur];
    const unsigned short* Bb = Bs[cur];
    int kb1 = (kt+1)*QBK, kb2 = (kt+2)*QBK;
    bf16x8 bfr[2], af[4];

    // ---- ph0: (mh=0, ks=0); load B[ks0]; stage a1(kt+1)
    #pragma unroll
    for(int ni=0;ni<2;ni++){
      int r = wc*32 + ni*16 + lr;
      bfr[ni] = *(const bf16x8*)&Bb[r*64 + ((g ^ (r&7))<<3)];
    }
    #pragma unroll
    for(int mi=0;mi<4;mi++){
      int r = wr*128 + mi*16 + lr;
      af[mi] = *(const bf16x8*)&Ab[r*64 + ((g ^ (r&7))<<3)];
    }
    if(kt < 15){ ST_A(nxt,kb1,1,0); ST_A(nxt,kb1,1,1); }
    __builtin_amdgcn_s_barrier();
    __builtin_amdgcn_s_setprio(1);
    #pragma unroll
    for(int mi=0;mi<4;mi++)
      #pragma unroll
      for(int ni=0;ni<2;ni++)
        acc[mi][ni] = __builtin_amdgcn_mfma_f32_16x16x32_bf16(af[mi], bfr[ni], acc[mi][ni], 0,0,0);
    __builtin_amdgcn_s_setprio(0);
    __builtin_amdgcn_s_barrier();

    // ---- ph1: (mh=1, ks=0); stage b0(kt+1)
    #pragma unroll
    for(int mi=0;mi<4;mi++){
      int r = wr*128 + (4+mi)*16 + lr;
      af[mi] = *(const bf16x8*)&Ab[r*64 + ((g ^ (r&7))<<3)];
    }
    if(kt < 15){ ST_B(nxt,kb1,0); }
    __builtin_amdgcn_s_barrier();
    __builtin_amdgcn_s_setprio(1);
    #pragma unroll
    for(int mi=0;mi<4;mi++)
      #pragma unroll
      for(int ni=0;ni<2;ni++)
        acc[4+mi][ni] = __builtin_amdgcn_mfma_f32_16x16x32_bf16(af[mi], bfr[ni], acc[4+mi][ni], 0,0,0);
    __builtin_amdgcn_s_setprio(0);
    __builtin_amdgcn_s_barrier();

    // ---- ph2: (mh=0, ks=1); load B[ks1]; stage b1(kt+1)
    #pragma unroll
    for(int ni=0;ni<2;ni++){
      int r = wc*32 + ni*16 + lr;
      bfr[ni] = *(const bf16x8*)&Bb[r*64 + (((4+g) ^ (r&7))<<3)];
    }
    #pragma unroll
    for(int mi=0;mi<4;mi++){
      int r = wr*128 + mi*16 + lr;
      af[mi] = *(const bf16x8*)&Ab[r*64 + (((4+g) ^ (r&7))<<3)];
    }
    if(kt < 15){ ST_B(nxt,kb1,1); }
    __builtin_amdgcn_s_barrier();
    __builtin_amdgcn_s_setprio(1);
    #pragma unroll
    for(int mi=0;mi<4;mi++)
      #pragma unroll
      for(int ni=0;ni<2;ni++)
        acc[mi][ni] = __builtin_amdgcn_mfma_f32_16x16x32_bf16(af[mi], bfr[ni], acc[mi][ni], 0,0,0);
    __builtin_amdgcn_s_setprio(0);
    __builtin_amdgcn_s_barrier();

    // ---- ph3: (mh=1, ks=1); stage a0(kt+2) into cur (A-half0 last read ph2)
    #pragma unroll
    for(int mi=0;mi<4;mi++){
      int r = wr*128 + (4+mi)*16 + lr;
      af[mi] = *(const bf16x8*)&Ab[r*64 + (((4+g) ^ (r&7))<<3)];
    }
    if(kt < 14){ ST_A(cur,kb2,0,0); ST_A(cur,kb2,0,1); }
    __builtin_amdgcn_s_barrier();
    __builtin_amdgcn_s_setprio(1);
    #pragma unroll
    for(int mi=0;mi<4;mi++)
      #pragma unroll
      for(int ni=0;ni<2;ni++)
        acc[4+mi][ni] = __builtin_amdgcn_mfma_f32_16x16x32_bf16(af[mi], bfr[ni], acc[4+mi][ni], 0,0,0);
    __builtin_amdgcn_s_setprio(0);
    if(kt < 14)       asm volatile("s_waitcnt vmcnt(2)" ::: "memory");  // kt+1 landed
    else if(kt == 14) asm volatile("s_waitcnt vmcnt(0)" ::: "memory");  // tail drain
    __builtin_amdgcn_s_barrier();
  }
  #undef ST_A
  #undef ST_B

  // epilogue: m = m0 + wr*128 + j*16 + g*4 + i ; n = n0 + wc*32 + ni*16 + lr
  int proj = n0 >> 10;
  const float* bias = (proj==0)?bq:((proj==1)?bk:bv);
  const float QSCALE = 0.18033688f;        // 0.125 * log2(e)
  #pragma unroll
  for(int j=0;j<8;j++){
    #pragma unroll
    for(int ni=0;ni<2;ni++){
      int ncol = n0 + wc*32 + ni*16 + lr;
      int hcol = ncol & 1023;
      int h = hcol >> 6, d = hcol & 63;
      float bval = bias[hcol];
      if(proj == 0){
        #pragma unroll
        for(int i=0;i<4;i++){
          int m = m0 + wr*128 + j*16 + g*4 + i;
          int b = m >> 10, s = m & 1023;
          q_ws[((size_t)(b*NH + h)*SQ + s)*HD + d] = f2bf((acc[j][ni][i] + bval)*QSCALE);
        }
      } else if(proj == 1){
        #pragma unroll
        for(int i=0;i<4;i++){
          int m = m0 + wr*128 + j*16 + g*4 + i;
          int b = m >> 10, s = m & 1023;
          k_ws[((size_t)(b*NH + h)*SQ + s)*HD + d] = f2bf(acc[j][ni][i] + bval);
        }
      } else {
        int m = m0 + wr*128 + j*16 + g*4;
        int b = m >> 10, s = m & 1023;
        u16x4 pk;
        #pragma unroll
        for(int i=0;i<4;i++) pk[i] = f2bf(acc[j][ni][i] + bval);
        *(u16x4*)&vt_ws[((size_t)(b*NH + h)*HD + d)*SQ + s] = pk;
      }
    }
  }
}

// ---------------- flash attention v3: 32x32 MFMA, P in registers ----------------
__global__ __launch_bounds__(512, 4) void k_attn(const unsigned short* __restrict__ q_ws,
                                                 const unsigned short* __restrict__ k_ws,
                                                 const unsigned short* __restrict__ vt_ws,
                                                 float* __restrict__ out){
  __shared__ __align__(16) unsigned short Ks[2][64*64];  // [token][d], chunk-swizzled
  __shared__ __align__(16) unsigned short Vs[2][64*64];  // [d][token], chunk-swizzled
  int tid = threadIdx.x, lane = tid & 63, wid = tid >> 6;
  int lq = lane & 31, h5 = lane >> 5;
  int bid = blockIdx.x;
  int swz = (bid & 7)*64 + (bid >> 3);     // XCD-bijective (512 = 8*64)
  int qb = swz & 3, bh = swz >> 2;
  int qw = qb*256 + wid*32;                // this wave's first q row
  const unsigned short* qp = q_ws + (size_t)bh*SQ*HD;
  const unsigned short* kp = k_ws + (size_t)bh*SQ*HD;
  const unsigned short* vp = vt_ws + (size_t)bh*HD*SQ;

  bf16x8 qf[4];
  #pragma unroll
  for(int dk=0;dk<4;dk++)
    qf[dk] = *(const bf16x8*)&qp[(size_t)(qw + lq)*HD + dk*16 + h5*8];

  int diag = qw >> 6;                      // wave-uniform constituent block

  int srow = tid >> 3;                     // 0..63
  int sch  = (tid & 7) ^ (srow & 7);

  f32x16 co[2];
  #pragma unroll
  for(int db=0;db<2;db++)
    #pragma unroll
    for(int r=0;r<16;r++) co[db][r] = 0.f;
  float lacc = 0.f;

  gload_lds16(kp + (size_t)srow*HD + sch*8, &Ks[0][tid*8]);
  gload_lds16(vp + (size_t)srow*SQ + sch*8, &Vs[0][tid*8]);
  __syncthreads();

  int cur = 0;
  for(int kt=0; kt<16; kt++){
    if(kt < 15){
      int kb = (kt+1)*64;
      gload_lds16(kp + (size_t)(kb+srow)*HD + sch*8, &Ks[cur^1][tid*8]);
      gload_lds16(vp + (size_t)srow*SQ + kb + sch*8, &Vs[cur^1][tid*8]);
    }
    float add = (kt == diag) ? 0.72134752f : 0.0f;

    #pragma unroll
    for(int tb=0; tb<2; tb++){
      f32x16 sc;
      #pragma unroll
      for(int r=0;r<16;r++) sc[r] = 0.f;
      int r0 = tb*32 + lq;
      #pragma unroll
      for(int dk=0;dk<4;dk++){
        bf16x8 kf = *(const bf16x8*)&Ks[cur][r0*64 + (((2*dk + h5) ^ (r0&7))<<3)];
        sc = __builtin_amdgcn_mfma_f32_32x32x16_bf16(kf, qf[dk], sc, 0,0,0);
      }
      unsigned int pk[8];
      #pragma unroll
      for(int w=0;w<8;w++){
        float lo = __builtin_amdgcn_exp2f(sc[2*w] + add);
        float hi = __builtin_amdgcn_exp2f(sc[2*w+1] + add);
        lacc += lo + hi;
        pk[w] = (unsigned int)f2bf(lo) | ((unsigned int)f2bf(hi) << 16);
      }
      asm volatile("v_permlane32_swap_b32 %0, %1" : "+v"(pk[0]), "+v"(pk[2]));
      asm volatile("v_permlane32_swap_b32 %0, %1" : "+v"(pk[1]), "+v"(pk[3]));
      asm volatile("v_permlane32_swap_b32 %0, %1" : "+v"(pk[4]), "+v"(pk[6]));
      asm volatile("v_permlane32_swap_b32 %0, %1" : "+v"(pk[5]), "+v"(pk[7]));
      u32x4 w0 = {pk[0], pk[1], pk[2], pk[3]};
      u32x4 w1 = {pk[4], pk[5], pk[6], pk[7]};
      bf16x8 pf0 = __builtin_bit_cast(bf16x8, w0);
      bf16x8 pf1 = __builtin_bit_cast(bf16x8, w1);

      #pragma unroll
      for(int db=0;db<2;db++){
        int vr = db*32 + lq;
        bf16x8 vf0 = *(const bf16x8*)&Vs[cur][vr*64 + (((4*tb + h5) ^ (vr&7))<<3)];
        co[db] = __builtin_amdgcn_mfma_f32_32x32x16_bf16(vf0, pf0, co[db], 0,0,0);
        bf16x8 vf1 = *(const bf16x8*)&Vs[cur][vr*64 + (((4*tb + 2 + h5) ^ (vr&7))<<3)];
        co[db] = __builtin_amdgcn_mfma_f32_32x32x16_bf16(vf1, pf1, co[db], 0,0,0);
      }
    }

    __syncthreads();
    cur ^= 1;
  }

  lacc += __shfl_xor(lacc, 32);
  float rl = 1.0f / lacc;

  int b = bh >> 4, h = bh & 15;
  size_t obase = ((size_t)(b*SQ + qw + lq))*HH + h*HD;
  #pragma unroll
  for(int db=0;db<2;db++){
    #pragma unroll
    for(int w=0;w<4;w++){
      f32x4 r;
      r[0] = co[db][4*w  ] * rl;
      r[1] = co[db][4*w+1] * rl;
      r[2] = co[db][4*w+2] * rl;
      r[3] = co[db][4*w+3] * rl;
      *(f32x4*)&out[obase + db*32 + 8*w + 4*h5] = r;
    }
  }
}

extern "C" void kernel_launch(void* const* d_in, const int* in_sizes, int n_in,
                              void* d_out, int out_size, void* d_ws, size_t ws_size,
                              hipStream_t stream){
  const float* hs = (const float*)d_in[0];
  const float* Wq = (const float*)d_in[1];
  const float* bq = (const float*)d_in[2];
  const float* Wk = (const float*)d_in[3];
  const float* bk = (const float*)d_in[4];
  const float* Wv = (const float*)d_in[5];
  const float* bv = (const float*)d_in[6];
  float* out = (float*)d_out;

  unsigned char* ws = (unsigned char*)d_ws;
  const size_t NX = (size_t)8192*1024;
  unsigned short* xb    = (unsigned short*)ws;
  unsigned short* wt    = (unsigned short*)(ws + NX*2);
  unsigned short* q_ws  = (unsigned short*)(ws + NX*2 + (size_t)3*1024*1024*2);
  unsigned short* k_ws  = q_ws + NX;
  unsigned short* vt_ws = k_ws + NX;

  k_prep<<<7168, 256, 0, stream>>>(hs, xb, Wq, Wk, Wv, wt);
  k_qkv<<<768, 512, 0, stream>>>(xb, wt, bq, bk, bv, q_ws, k_ws, vt_ws);
  k_attn<<<512, 512, 0, stream>>>(q_ws, k_ws, vt_ws, out);
}